// Round 8
// baseline (140.663 us; speedup 1.0000x reference)
//
#include <hip/hip_runtime.h>

typedef _Float16 half_t;
typedef _Float16 half2_t __attribute__((ext_vector_type(2)));

#define KW   31
#define R    15
#define NP   32
#define HH   512
#define WW   512
#define NB   4

#define TX   8               // threads in x, each handles 8 consecutive px
#define TY   32              // thread rows (1 px row each)
#define PXW  (TX * 8)        // 64 pixels wide per block
#define EXT_Y (TY + 2*R)     // 62
#define EXT_X (PXW + 2*R)    // 94 px = 47 half2 dwords used
#define DW_ROW 47
#define DSTRIDE 49           // ≡17 mod 32: 8-row x 8-lane wave -> exact 2-way per read (free)

#if __has_builtin(__builtin_amdgcn_fdot2)
#define DOT2(a, b, c) __builtin_amdgcn_fdot2((a), (b), (c), false)
#else
#define DOT2(a, b, c) ((c) + (float)(a).x * (float)(b).x + (float)(a).y * (float)(b).y)
#endif

// (256,1): (256,2) empirically caps VGPR at 128 and spills (R2/R5).
__global__ __launch_bounds__(256, 1) void defocus_kernel(
    const float* __restrict__ sharp, const float* __restrict__ coc_map,
    float* __restrict__ out)
{
    __shared__ float gT[KW][NP];     // gT[tap][plane]; bank == plane -> conflict-free
    __shared__ float bnd[KW];
    __shared__ half2_t tile[3][EXT_Y][DSTRIDE];   // ~36.5 KB

    const int tid = threadIdx.x;

    // ---- per-plane 1-D Gaussian weights (zero-padded to 31, centered at R) ----
    if (tid < NP) {
        const int p = tid;
        const double step = 50.0 / 31.0;
        const float pv = (p == 31) ? 50.0f : (float)((double)p * step);
        #pragma unroll
        for (int j = 0; j < KW; ++j) gT[j][p] = 0.0f;
        if (pv < 0.5f) {
            gT[R][p] = 1.0f;
        } else {
            const double coc   = (double)pv;
            const double sigma = coc / 2.355;
            int k = (int)(2.0 * coc + 1.0);
            if ((k & 1) == 0) k += 1;
            if (k > KW) k = KW;
            const int half = k >> 1;
            float s = 0.0f;
            for (int j = 0; j < k; ++j) {
                double c = (double)(j - half);
                s += (float)exp(-(c * c) / (2.0 * sigma * sigma));
            }
            for (int j = 0; j < k; ++j) {
                double c = (double)(j - half);
                gT[R - half + j][p] = (float)exp(-(c * c) / (2.0 * sigma * sigma)) / s;
            }
        }
    }
    // ---- bucket boundaries, bit-exact float32((planes[i]+planes[i+1])/2) ----
    if (tid < KW) {
        const double step = 50.0 / 31.0;
        const float pa = (float)((double)tid * step);
        const float pb = (tid == 30) ? 50.0f : (float)((double)(tid + 1) * step);
        bnd[tid] = (pa + pb) * 0.5f;
    }

    // ---- stage input tile (+halo) as packed f16 pairs, zero outside image ----
    const int bx = blockIdx.x, by = blockIdx.y, bb = blockIdx.z;
    const int x0 = bx * PXW - R, y0 = by * TY - R;
    for (int idx = tid; idx < EXT_Y * DW_ROW; idx += 256) {
        const int r = idx / DW_ROW, dw = idx - r * DW_ROW;
        const int gy = y0 + r;
        const int gxa = x0 + 2 * dw, gxb = gxa + 1;
        const bool oky = ((unsigned)gy < HH);
        #pragma unroll
        for (int ch = 0; ch < 3; ++ch) {
            const float* src = &sharp[(((size_t)bb * 3 + ch) * HH + gy) * WW];
            const float va = (oky && (unsigned)gxa < WW) ? src[gxa] : 0.0f;
            const float vb = (oky && (unsigned)gxb < WW) ? src[gxb] : 0.0f;
            half2_t h; h.x = (half_t)va; h.y = (half_t)vb;
            tile[ch][r][dw] = h;
        }
    }
    __syncthreads();

    // ---- this thread's 8 pixels ----
    const int tx = tid & (TX - 1), ty = tid >> 3;
    const int ox = bx * PXW + 8 * tx, oy = by * TY + ty;

    // plane select per pixel (exact reference semantics: count coc > bnd[k])
    const float* cocrow = &coc_map[((size_t)bb * HH + oy) * WW + ox];
    const float4 c0 = *(const float4*)cocrow;
    const float4 c1 = *(const float4*)(cocrow + 4);
    const float cocv[8] = {c0.x, c0.y, c0.z, c0.w, c1.x, c1.y, c1.z, c1.w};
    int plane[8];
    #pragma unroll
    for (int j = 0; j < 8; ++j) {
        int p = 0;
        #pragma unroll
        for (int k = 0; k < KW; ++k) p += (cocv[j] > bnd[k]) ? 1 : 0;
        plane[j] = p;
    }

    // ---- pack per-pixel x-weights as half2 aligned to the shared 19-dword window ----
    // window dword k (k=0..18) holds tile px (8tx+2k, 8tx+2k+1); pixel j's tap d
    // sits at dword k with 2k+h-j==d. Pixel j uses dwords (j>>1)..(j>>1)+15.
    half2_t wgt[8][16];
    #pragma unroll
    for (int j = 0; j < 8; ++j) {
        const int kmin = j >> 1;
        #pragma unroll
        for (int i = 0; i < 16; ++i) {
            const int k = kmin + i;
            const int d0 = 2 * k - j, d1 = 2 * k + 1 - j;
            half2_t h;
            h.x = (d0 >= 0 && d0 <= 30) ? (half_t)gT[d0][plane[j]] : (half_t)0.0f;
            h.y = (d1 >= 0 && d1 <= 30) ? (half_t)gT[d1][plane[j]] : (half_t)0.0f;
            wgt[j][i] = h;
        }
    }

    // ---- separable accumulation: dy outer (y-weights once), ch inner ----
    float acc[3][8];
    #pragma unroll
    for (int ch = 0; ch < 3; ++ch)
        #pragma unroll
        for (int j = 0; j < 8; ++j) acc[ch][j] = 0.0f;

    #pragma unroll 1
    for (int dy = 0; dy < KW; ++dy) {
        float wy[8];
        #pragma unroll
        for (int j = 0; j < 8; ++j) wy[j] = gT[dy][plane[j]];   // bank==plane, free
        #pragma unroll
        for (int ch = 0; ch < 3; ++ch) {
            const half2_t* rp = &tile[ch][ty + dy][4 * tx];
            half2_t win[19];
            #pragma unroll
            for (int k = 0; k < 19; ++k) win[k] = rp[k];
            #pragma unroll
            for (int j = 0; j < 8; ++j) {
                float s = 0.0f;
                #pragma unroll
                for (int i = 0; i < 16; ++i)
                    s = DOT2(win[(j >> 1) + i], wgt[j][i], s);
                acc[ch][j] = fmaf(wy[j], s, acc[ch][j]);
            }
        }
    }

    // ---- store 8 px per channel as two float4 ----
    #pragma unroll
    for (int ch = 0; ch < 3; ++ch) {
        float* dst = &out[(((size_t)bb * 3 + ch) * HH + oy) * WW + ox];
        *(float4*)dst       = make_float4(acc[ch][0], acc[ch][1], acc[ch][2], acc[ch][3]);
        *(float4*)(dst + 4) = make_float4(acc[ch][4], acc[ch][5], acc[ch][6], acc[ch][7]);
    }
}

extern "C" void kernel_launch(void* const* d_in, const int* in_sizes, int n_in,
                              void* d_out, int out_size, void* d_ws, size_t ws_size,
                              hipStream_t stream) {
    const float* sharp = (const float*)d_in[0];
    const float* coc   = (const float*)d_in[1];
    float* outp        = (float*)d_out;
    dim3 grid(WW / PXW, HH / TY, NB);
    defocus_kernel<<<grid, dim3(256), 0, stream>>>(sharp, coc, outp);
}